// Round 2
// baseline (823.457 us; speedup 1.0000x reference)
//
#include <hip/hip_runtime.h>
#include <hip/hip_bf16.h>

#define SEQ 2048

__device__ __forceinline__ float silu_f(float x){ return x / (1.f + __expf(-x)); }

// ---------------- K0: transpose hidden (b,l,d) -> hidT (b,d,l) fp32 ----------------
__global__ __launch_bounds__(256) void k_transpose(const float* __restrict__ hid,
                                                   float* __restrict__ hidT){
    int t = blockIdx.x * 256 + threadIdx.x;           // (b,d,l), l fastest; 2*256*2048
    int l = t & 2047; int d = (t >> 11) & 255; int b = t >> 19;
    hidT[t] = hid[(b * 2048 + l) * 256 + d];
}

// ---------------- K1: xz[b][e][l] = sum_d hidT[b][d][l] * in_w[e][d] ----------------
__global__ __launch_bounds__(256) void k_ingemm(const float* __restrict__ hidT,
                                                const float* __restrict__ in_w,
                                                float* __restrict__ xz){
    int lane = threadIdx.x & 63;
    int ew = threadIdx.x >> 6;                         // 0..3
    int bid = blockIdx.x;                              // 2 * 32 * 32
    int lblk = bid & 31; int eblk = (bid >> 5) & 31; int b = bid >> 10;
    int l = lblk * 64 + lane;
    int e0 = eblk * 32 + ew * 8;
    const float* hrow = hidT + b * 256 * SEQ + l;
    float acc[8] = {0,0,0,0,0,0,0,0};
    for (int d = 0; d < 256; ++d) {
        float hv = hrow[d * SEQ];
        #pragma unroll
        for (int k = 0; k < 8; ++k)
            acc[k] = fmaf(in_w[(e0 + k) * 256 + d], hv, acc[k]);
    }
    #pragma unroll
    for (int k = 0; k < 8; ++k)
        xz[(b * 1024 + e0 + k) * SEQ + l] = acc[k];
}

// ---------------- K2: causal dwconv(K=4) + silu over branch-permuted x -> u ----------------
__global__ __launch_bounds__(256) void k_conv(const float* __restrict__ xz,
                                              const float* __restrict__ conv_w,
                                              const float* __restrict__ conv_b,
                                              float* __restrict__ u){
    int row = blockIdx.x;                              // ib*512 + d, ib = i*2+b
    int d = row & 511; int ib = row >> 9; int b = ib & 1; int i = ib >> 1;
    const int shtab[3] = {11, 6, 4};
    int sh = shtab[i >> 1];
    int mask = (1 << sh) - 1;
    int mul = SEQ >> sh;
    int flip = i & 1;
    float w0 = conv_w[(i * 512 + d) * 4 + 0];
    float w1 = conv_w[(i * 512 + d) * 4 + 1];
    float w2 = conv_w[(i * 512 + d) * 4 + 2];
    float w3 = conv_w[(i * 512 + d) * 4 + 3];
    float cb = conv_b[i * 512 + d];
    const float* xrow = xz + (b * 1024 + d) * SEQ;
    float* urow = u + row * SEQ;
    for (int k = 0; k < 8; ++k) {
        int j = (int)threadIdx.x + k * 256;
        float acc = cb;
        #pragma unroll
        for (int m = 0; m < 4; ++m) {
            int idx = j - 3 + m;
            float xv = 0.f;
            if (idx >= 0) {
                int jj = flip ? (SEQ - 1 - idx) : idx;
                int l = (jj & mask) * mul + (jj >> sh);
                xv = xrow[l];
            }
            float wm = (m == 0) ? w0 : (m == 1) ? w1 : (m == 2) ? w2 : w3;
            acc = fmaf(wm, xv, acc);
        }
        urow[j] = silu_f(acc);
    }
}

// ---------------- K2b: silu(z) in place on z-half of xz ----------------
__global__ __launch_bounds__(256) void k_siluz(float* __restrict__ xz){
    int t = blockIdx.x * 256 + threadIdx.x;            // (b,d,l); 2*512*2048
    int l = t & 2047; int bd = t >> 11; int d = bd & 511; int b = bd >> 9;
    float* p = xz + (b * 1024 + 512 + d) * SEQ + l;
    float v = *p;
    *p = silu_f(v);
}

// ---------------- K3: x_dbl[ib][r][j] = sum_d xproj_w[i][r][d] * u[ib][d][j] ----------------
__global__ __launch_bounds__(256) void k_xproj(const float* __restrict__ u,
                                               const float* __restrict__ xw,
                                               float* __restrict__ xdbl){
    int t = blockIdx.x * 256 + threadIdx.x;            // (ib*6+rb)*2048 + j ; 12*6*2048
    int j = t & 2047;
    int g = t >> 11;
    int rb = g % 6; int ib = g / 6; int i = ib >> 1;
    const float* ub = u + ib * 512 * SEQ + j;
    const float* wb = xw + (i * 48 + rb * 8) * 512;
    float acc[8] = {0,0,0,0,0,0,0,0};
    for (int dd = 0; dd < 512; ++dd) {
        float uv = ub[dd * SEQ];
        #pragma unroll
        for (int k2 = 0; k2 < 8; ++k2)
            acc[k2] = fmaf(wb[k2 * 512 + dd], uv, acc[k2]);
    }
    float* ob = xdbl + (ib * 48 + rb * 8) * SEQ + j;
    #pragma unroll
    for (int k2 = 0; k2 < 8; ++k2) ob[k2 * SEQ] = acc[k2];
}

// ---------------- K4: delta[ib][d][j] = softplus(dtlow . dt_w[d] + dt_b[d]) ----------------
__global__ __launch_bounds__(256) void k_delta(const float* __restrict__ xdbl,
                                               const float* __restrict__ dt_w,
                                               const float* __restrict__ dt_b,
                                               float* __restrict__ delta){
    int t = blockIdx.x * 256 + threadIdx.x;            // (ib*128 + d4)*2048 + j
    int j = t & 2047;
    int d4 = (t >> 11) & 127;
    int ib = t >> 18; int i = ib >> 1;
    const float* dl = xdbl + ib * 48 * SEQ + j;        // dtlow rows r=0..15
    const float* w = dt_w + (i * 512 + d4 * 4) * 16;
    float a0 = 0, a1 = 0, a2 = 0, a3 = 0;
    #pragma unroll
    for (int r = 0; r < 16; ++r) {
        float v = dl[r * SEQ];
        a0 = fmaf(w[r],      v, a0);
        a1 = fmaf(w[16 + r], v, a1);
        a2 = fmaf(w[32 + r], v, a2);
        a3 = fmaf(w[48 + r], v, a3);
    }
    float accs[4] = {a0, a1, a2, a3};
    #pragma unroll
    for (int k = 0; k < 4; ++k) {
        float x = accs[k] + dt_b[i * 512 + d4 * 4 + k];
        float sp = (x > 20.f) ? x : log1pf(__expf(x));
        delta[(ib * 512 + d4 * 4 + k) * SEQ + j] = sp;
    }
}

// ---------------- K5: SSM scan. 16 lanes per (ib,d) worker, state n per lane. y in-place over u ----------------
__global__ __launch_bounds__(256) void k_scan(float* __restrict__ u,
                                              const float* __restrict__ delta,
                                              const float* __restrict__ xdbl,
                                              const float* __restrict__ A_log,
                                              const float* __restrict__ D_skip){
    int gid = blockIdx.x * 256 + threadIdx.x;
    int w = gid >> 4;                                  // worker: ib*512 + d, 0..6143
    int n = gid & 15;                                  // state
    int d = w & 511; int ib = w >> 9; int i = ib >> 1;
    float A = -__expf(A_log[(i * 512 + d) * 16 + n]);
    float Dd = D_skip[i * 512 + d];
    const float4* d4 = (const float4*)(delta + w * SEQ);
    float4* u4 = (float4*)(u + w * SEQ);
    const float4* B4 = (const float4*)(xdbl + (ib * 48 + 16 + n) * SEQ);
    const float4* C4 = (const float4*)(xdbl + (ib * 48 + 32 + n) * SEQ);
    float h = 0.f;
    for (int jb = 0; jb < SEQ / 4; ++jb) {
        float4 dv = d4[jb];
        float4 uv = u4[jb];
        float4 Bv = B4[jb];
        float4 Cv = C4[jb];
        float4 yo;
        {
            float dA = __expf(dv.x * A);
            h = fmaf(dA, h, dv.x * uv.x * Bv.x);
            float yp = h * Cv.x;
            yp += __shfl_xor(yp, 1, 16); yp += __shfl_xor(yp, 2, 16);
            yp += __shfl_xor(yp, 4, 16); yp += __shfl_xor(yp, 8, 16);
            yo.x = fmaf(uv.x, Dd, yp);
        }
        {
            float dA = __expf(dv.y * A);
            h = fmaf(dA, h, dv.y * uv.y * Bv.y);
            float yp = h * Cv.y;
            yp += __shfl_xor(yp, 1, 16); yp += __shfl_xor(yp, 2, 16);
            yp += __shfl_xor(yp, 4, 16); yp += __shfl_xor(yp, 8, 16);
            yo.y = fmaf(uv.y, Dd, yp);
        }
        {
            float dA = __expf(dv.z * A);
            h = fmaf(dA, h, dv.z * uv.z * Bv.z);
            float yp = h * Cv.z;
            yp += __shfl_xor(yp, 1, 16); yp += __shfl_xor(yp, 2, 16);
            yp += __shfl_xor(yp, 4, 16); yp += __shfl_xor(yp, 8, 16);
            yo.z = fmaf(uv.z, Dd, yp);
        }
        {
            float dA = __expf(dv.w * A);
            h = fmaf(dA, h, dv.w * uv.w * Bv.w);
            float yp = h * Cv.w;
            yp += __shfl_xor(yp, 1, 16); yp += __shfl_xor(yp, 2, 16);
            yp += __shfl_xor(yp, 4, 16); yp += __shfl_xor(yp, 8, 16);
            yo.w = fmaf(uv.w, Dd, yp);
        }
        if (n == 0) u4[jb] = yo;
    }
}

// ---------------- K6: un-permute, sum branches, apply silu(z) ----------------
__global__ __launch_bounds__(256) void k_gather(const float* __restrict__ y,
                                                const float* __restrict__ xz,
                                                float* __restrict__ total){
    int t = blockIdx.x * 256 + threadIdx.x;            // (b,d,l); 2*512*2048
    int l = t & 2047; int bd = t >> 11; int d = bd & 511; int b = bd >> 9;
    int j2 = ((l & 31) << 6) + (l >> 5);               // interleave ns=64 inverse-restore
    int j4 = ((l & 127) << 4) + (l >> 7);              // interleave ns=16 inverse-restore
    long base = (long)(b * 512 + d) * SEQ;
    const float* y0 = y + (0 * 1024) * SEQ + base;
    const float* y1 = y + (1 * 1024) * SEQ + base;
    const float* y2 = y + (2 * 1024) * SEQ + base;
    const float* y3 = y + (3 * 1024) * SEQ + base;
    const float* y4 = y + (4 * 1024) * SEQ + base;
    const float* y5 = y + (5 * 1024) * SEQ + base;
    float s_fwd = y0[l] + y1[2047 - l] + y2[j2] + y4[j4];
    float s_bwd = y3[j2] + y5[j4];
    const float* zrow = xz + (b * 1024 + 512 + d) * SEQ;
    total[(b * 512 + d) * SEQ + l] = fmaf(s_fwd, zrow[l], s_bwd * zrow[2047 - l]);
}

// ---------------- K7: out[b][l][o] = sum_d total[b][d][l] * out_w[o][d] ----------------
__global__ __launch_bounds__(256) void k_outgemm(const float* __restrict__ total,
                                                 const float* __restrict__ out_w,
                                                 float* __restrict__ out){
    int lane = threadIdx.x & 63;
    int ow = threadIdx.x >> 6;                         // 0..3
    int bid = blockIdx.x;                              // 2*8*32
    int lblk = bid & 31; int oblk = (bid >> 5) & 7; int b = bid >> 8;
    int l = lblk * 64 + lane;
    int o0 = oblk * 32 + ow * 8;
    const float* trow = total + b * 512 * SEQ + l;
    float acc[8] = {0,0,0,0,0,0,0,0};
    for (int d = 0; d < 512; ++d) {
        float tv = trow[d * SEQ];
        #pragma unroll
        for (int k = 0; k < 8; ++k)
            acc[k] = fmaf(out_w[(o0 + k) * 512 + d], tv, acc[k]);
    }
    float* orow = out + ((long)(b * 2048 + l)) * 256 + o0;
    #pragma unroll
    for (int k = 0; k < 8; ++k) orow[k] = acc[k];
}

extern "C" void kernel_launch(void* const* d_in, const int* in_sizes, int n_in,
                              void* d_out, int out_size, void* d_ws, size_t ws_size,
                              hipStream_t stream) {
    const float* hid    = (const float*)d_in[0];
    const float* in_w   = (const float*)d_in[1];
    const float* out_w  = (const float*)d_in[2];
    const float* conv_w = (const float*)d_in[3];
    const float* conv_b = (const float*)d_in[4];
    const float* xw     = (const float*)d_in[5];
    const float* dt_w   = (const float*)d_in[6];
    const float* dt_b   = (const float*)d_in[7];
    const float* A_log  = (const float*)d_in[8];
    const float* D_skip = (const float*)d_in[9];
    float* out = (float*)d_out;

    // ws layout (floats)
    const size_t off_xz    = 0;                        // 2*1024*2048  = 4,194,304
    const size_t off_u     = 4194304;                  // 12*512*2048  = 12,582,912
    const size_t off_xdbl  = 16777216;                 // 12*48*2048   = 1,179,648
    const size_t off_delta = 17956864;                 // 12,582,912
    const size_t off_total = 30539776;                 // 2*512*2048   = 2,097,152
    const size_t need = (size_t)32636928 * 4;
    if (ws_size < need) return;                        // fail loudly (zeros) rather than corrupt

    float* xz    = (float*)d_ws + off_xz;
    float* u     = (float*)d_ws + off_u;
    float* xdbl  = (float*)d_ws + off_xdbl;
    float* delta = (float*)d_ws + off_delta;
    float* total = (float*)d_ws + off_total;
    float* hidT  = total;                              // alias: free until k_gather

    k_transpose<<<4096, 256, 0, stream>>>(hid, hidT);
    k_ingemm  <<<2048, 256, 0, stream>>>(hidT, in_w, xz);
    k_conv    <<<6144, 256, 0, stream>>>(xz, conv_w, conv_b, u);
    k_siluz   <<<8192, 256, 0, stream>>>(xz);
    k_xproj   <<<576,  256, 0, stream>>>(u, xw, xdbl);
    k_delta   <<<12288,256, 0, stream>>>(xdbl, dt_w, dt_b, delta);
    k_scan    <<<384,  256, 0, stream>>>(u, delta, xdbl, A_log, D_skip);
    k_gather  <<<8192, 256, 0, stream>>>(u, xz, total);
    k_outgemm <<<512,  256, 0, stream>>>(total, out_w, out);
}